// Round 6
// baseline (285.700 us; speedup 1.0000x reference)
//
#include <hip/hip_runtime.h>
#include <hip/hip_fp16.h>

#define NF 128           // feature dim (fixed by problem)
#define GEMM_ROWS 32     // feature rows per block in GEMM
#define SCHUNK 512       // counts handled per scan block (256 threads x 2)
#define NWIN 8           // dst windows for XCD-local fill (== # XCDs)
#define FCHUNK 2048      // edges per fill chunk

// ---------------------------------------------------------------------------
// Detect whether edge_index is int64 (high 32-bit words all zero) or int32.
// ---------------------------------------------------------------------------
__global__ __launch_bounds__(64) void detect_kernel(const int* __restrict__ ei_words,
                                                    int* __restrict__ flag) {
    if (threadIdx.x == 0) {
        int all_zero = 1;
        for (int i = 0; i < 64; ++i) {
            if (ei_words[2 * i + 1] != 0) { all_zero = 0; break; }
        }
        *flag = all_zero;  // 1 => int64 layout
    }
}

__device__ __forceinline__ int load_idx(const void* ei_raw, long long pos, int is64) {
    if (is64) return (int)((const long long*)ei_raw)[pos];
    return ((const int*)ei_raw)[pos];
}

// non-temporal variant: streaming reads with no L2 retention (gfx950 nt flag)
__device__ __forceinline__ int load_idx_nt(const void* ei_raw, long long pos, int is64) {
    if (is64) return (int)__builtin_nontemporal_load((const long long*)ei_raw + pos);
    return __builtin_nontemporal_load((const int*)ei_raw + pos);
}

// ---------------------------------------------------------------------------
__global__ __launch_bounds__(256) void zero_kernel(int* __restrict__ p, int n) {
    int i = blockIdx.x * 256 + threadIdx.x;
    if (i < n) p[i] = 0;
}

// counts[dst]++ for every edge (nt read: dst stream has no reuse)
__global__ __launch_bounds__(256) void count_kernel(const void* __restrict__ ei_raw,
                                                    int* __restrict__ counts, int E,
                                                    const int* __restrict__ flag,
                                                    const int* __restrict__ nm) {
    if (*nm <= 1) return;
    int e = blockIdx.x * 256 + threadIdx.x;
    if (e >= E) return;
    int dst = load_idx_nt(ei_raw, e, *flag);
    atomicAdd(&counts[dst], 1);
}

// ---------------------------------------------------------------------------
// 3-phase multi-block exclusive scan of counts[N] -> offs[N+1], cursor[N]
// ---------------------------------------------------------------------------
__global__ __launch_bounds__(256) void scanA_kernel(const int* __restrict__ counts,
                                                    int* __restrict__ bsum, int N) {
    int t = threadIdx.x;
    int i0 = blockIdx.x * SCHUNK + t * 2;
    int s = 0;
    if (i0 < N) s += counts[i0];
    if (i0 + 1 < N) s += counts[i0 + 1];
    __shared__ int l[256];
    l[t] = s;
    __syncthreads();
    for (int o = 128; o > 0; o >>= 1) {
        if (t < o) l[t] += l[t + o];
        __syncthreads();
    }
    if (t == 0) bsum[blockIdx.x] = l[0];
}

__global__ __launch_bounds__(1024) void scanB_kernel(const int* __restrict__ bsum,
                                                     int* __restrict__ boff,
                                                     int* __restrict__ offs,
                                                     int NB, int N) {
    __shared__ int l[1024];
    int t = threadIdx.x;
    int v = (t < NB) ? bsum[t] : 0;
    l[t] = v;
    __syncthreads();
    for (int o = 1; o < 1024; o <<= 1) {
        int x = (t >= o) ? l[t - o] : 0;
        __syncthreads();
        l[t] += x;
        __syncthreads();
    }
    if (t < NB) boff[t] = l[t] - v;     // exclusive
    if (t == 1023) offs[N] = l[1023];   // grand total
}

__global__ __launch_bounds__(256) void scanC_kernel(const int* __restrict__ counts,
                                                    const int* __restrict__ boff,
                                                    int* __restrict__ offs,
                                                    int* __restrict__ cursor, int N) {
    int t = threadIdx.x;
    int i0 = blockIdx.x * SCHUNK + t * 2;
    int c0 = (i0 < N) ? counts[i0] : 0;
    int c1 = (i0 + 1 < N) ? counts[i0 + 1] : 0;
    int s = c0 + c1;
    __shared__ int l[256];
    l[t] = s;
    __syncthreads();
    for (int o = 1; o < 256; o <<= 1) {
        int x = (t >= o) ? l[t - o] : 0;
        __syncthreads();
        l[t] += x;
        __syncthreads();
    }
    int base = boff[blockIdx.x] + (l[t] - s);
    if (i0 < N)     { offs[i0] = base;          cursor[i0] = base; }
    if (i0 + 1 < N) { offs[i0 + 1] = base + c0; cursor[i0 + 1] = base + c0; }
}

// ---------------------------------------------------------------------------
// counting-sort edges into (src_bits, w) records grouped by dst.
// XCD-windowed + NON-TEMPORAL streaming reads: the ei/ew streams carry the
// nt flag so they don't evict the window's 1.6MB of dirty srcw lines from
// the XCD's 4MB L2 -> ~8 records per 64B line merge before one writeback.
// srcw stores stay cached (they must allocate in L2 to merge).
// ---------------------------------------------------------------------------
__global__ __launch_bounds__(256) void fill_kernel(const void* __restrict__ ei_raw,
                                                   const float* __restrict__ ew,
                                                   int* __restrict__ cursor,
                                                   float2* __restrict__ srcw, int E,
                                                   int N,
                                                   const int* __restrict__ flag,
                                                   const int* __restrict__ nm) {
    if (*nm <= 1) return;
    int is64 = *flag;
    int win   = blockIdx.x % NWIN;          // -> XCD (round-robin heuristic)
    int chunk = blockIdx.x / NWIN;
    int span = (N + NWIN - 1) / NWIN;
    int lo = win * span;
    int hi = min(lo + span, N);
    int ebeg = chunk * FCHUNK;
    int eend = min(ebeg + FCHUNK, E);
    for (int e = ebeg + threadIdx.x; e < eend; e += 256) {
        int dst = load_idx_nt(ei_raw, e, is64);
        if (dst < lo || dst >= hi) continue;
        int src = load_idx_nt(ei_raw, (long long)E + e, is64);
        float w = __builtin_nontemporal_load(ew + e);
        int pos = atomicAdd(&cursor[dst], 1);
        srcw[pos] = make_float2(__int_as_float(src), w);
    }
}

// ---------------------------------------------------------------------------
// gather: one 64-lane wave per dst row; lane owns a half2 of the 128-wide row.
// out[row] = bias + sum_e w_e * support_h[src_e]   (fp16 rows, fp32 accumulate)
// ---------------------------------------------------------------------------
__global__ __launch_bounds__(256) void gather_kernel(const int* __restrict__ offs,
                                                     const float2* __restrict__ srcw,
                                                     const __half* __restrict__ support,
                                                     const float* __restrict__ bias,
                                                     const float* __restrict__ feat,
                                                     float* __restrict__ out, int N,
                                                     const int* __restrict__ nm) {
    int gwave = (blockIdx.x * 256 + threadIdx.x) >> 6;
    int lane = threadIdx.x & 63;
    if (gwave >= N) return;
    size_t rowoff = (size_t)gwave * NF + lane * 2;
    if (*nm <= 1) {  // identity path
        *(float2*)(out + rowoff) = *(const float2*)(feat + rowoff);
        return;
    }
    int beg = offs[gwave];
    int end = offs[gwave + 1];
    float2 acc = *(const float2*)(bias + lane * 2);
    int e = beg;
    for (; e + 3 < end; e += 4) {
        float2 sw0 = srcw[e];
        float2 sw1 = srcw[e + 1];
        float2 sw2 = srcw[e + 2];
        float2 sw3 = srcw[e + 3];
        __half2 h0 = ((const __half2*)(support + (size_t)__float_as_int(sw0.x) * NF))[lane];
        __half2 h1 = ((const __half2*)(support + (size_t)__float_as_int(sw1.x) * NF))[lane];
        __half2 h2 = ((const __half2*)(support + (size_t)__float_as_int(sw2.x) * NF))[lane];
        __half2 h3 = ((const __half2*)(support + (size_t)__float_as_int(sw3.x) * NF))[lane];
        float2 s0 = __half22float2(h0);
        float2 s1 = __half22float2(h1);
        float2 s2 = __half22float2(h2);
        float2 s3 = __half22float2(h3);
        acc.x = fmaf(sw0.y, s0.x, acc.x);  acc.y = fmaf(sw0.y, s0.y, acc.y);
        acc.x = fmaf(sw1.y, s1.x, acc.x);  acc.y = fmaf(sw1.y, s1.y, acc.y);
        acc.x = fmaf(sw2.y, s2.x, acc.x);  acc.y = fmaf(sw2.y, s2.y, acc.y);
        acc.x = fmaf(sw3.y, s3.x, acc.x);  acc.y = fmaf(sw3.y, s3.y, acc.y);
    }
    for (; e < end; ++e) {
        float2 sw = srcw[e];
        __half2 h = ((const __half2*)(support + (size_t)__float_as_int(sw.x) * NF))[lane];
        float2 s = __half22float2(h);
        acc.x = fmaf(sw.y, s.x, acc.x);
        acc.y = fmaf(sw.y, s.y, acc.y);
    }
    *(float2*)(out + rowoff) = acc;
}

// ---------------------------------------------------------------------------
// support = feature @ W (fp32 vector ALU, fp16 output rows)
// ---------------------------------------------------------------------------
__global__ __launch_bounds__(256) void gemm_kernel(const float* __restrict__ feat,
                                                   const float* __restrict__ W,
                                                   __half* __restrict__ support,
                                                   int N) {
    __shared__ float Flds[GEMM_ROWS * NF];   // 16 KB
    __shared__ float Wlds[32 * NF];          // 16 KB
    int tid = threadIdx.x;
    int row0 = blockIdx.x * GEMM_ROWS;

    const float4* f4p = (const float4*)(feat + (size_t)row0 * NF);
    float4* Fl4 = (float4*)Flds;
#pragma unroll
    for (int i = 0; i < 4; ++i) Fl4[tid + i * 256] = f4p[tid + i * 256];

    int tx = tid & 31;
    int ty = tid >> 5;
    float acc[4][4] = {{0.f}};

    float4* Wl4 = (float4*)Wlds;
    for (int kt = 0; kt < 4; ++kt) {
        __syncthreads();
        const float4* w4p = (const float4*)(W + kt * 32 * NF);
#pragma unroll
        for (int i = 0; i < 4; ++i) Wl4[tid + i * 256] = w4p[tid + i * 256];
        __syncthreads();
#pragma unroll
        for (int kk = 0; kk < 32; ++kk) {
            int k = kt * 32 + kk;
            float4 wv = *(const float4*)(Wlds + kk * NF + tx * 4);
#pragma unroll
            for (int i = 0; i < 4; ++i) {
                float fv = Flds[(ty * 4 + i) * NF + k];
                acc[i][0] += fv * wv.x;
                acc[i][1] += fv * wv.y;
                acc[i][2] += fv * wv.z;
                acc[i][3] += fv * wv.w;
            }
        }
    }

#pragma unroll
    for (int i = 0; i < 4; ++i) {
        int row = row0 + ty * 4 + i;
        if (row < N) {
            __half2 h0 = __floats2half2_rn(acc[i][0], acc[i][1]);
            __half2 h1 = __floats2half2_rn(acc[i][2], acc[i][3]);
            __half2* sp = (__half2*)(support + (size_t)row * NF + tx * 4);
            sp[0] = h0;
            sp[1] = h1;
        }
    }
}

// ---------------------------------------------------------------------------
// Fallback (round-1) kernels in case ws_size is too small for CSR buffers.
// ---------------------------------------------------------------------------
__global__ __launch_bounds__(256) void init_kernel(const float* __restrict__ bias,
                                                   const float* __restrict__ feat,
                                                   float* __restrict__ out,
                                                   int total4,
                                                   const int* __restrict__ nm) {
    int idx = blockIdx.x * 256 + threadIdx.x;
    if (idx >= total4) return;
    if (*nm > 1)
        ((float4*)out)[idx] = ((const float4*)bias)[idx & (NF / 4 - 1)];
    else
        ((float4*)out)[idx] = ((const float4*)feat)[idx];
}

__global__ __launch_bounds__(256) void scatter_kernel(const void* __restrict__ ei_raw,
                                                      const float* __restrict__ ew,
                                                      const __half* __restrict__ support,
                                                      float* __restrict__ out,
                                                      int E,
                                                      const int* __restrict__ flag,
                                                      const int* __restrict__ nm) {
    if (*nm <= 1) return;
    int is64 = *flag;
    long long idx = (long long)blockIdx.x * 256 + threadIdx.x;
    int e = (int)(idx >> 5);
    if (e >= E) return;
    int f4 = (int)(idx & 31);
    long long dst = load_idx(ei_raw, e, is64);
    long long src = load_idx(ei_raw, (long long)E + e, is64);
    float w = ew[e];
    __half2 h0 = ((const __half2*)(support + src * NF + f4 * 4))[0];
    __half2 h1 = ((const __half2*)(support + src * NF + f4 * 4))[1];
    float2 s0 = __half22float2(h0);
    float2 s1 = __half22float2(h1);
    float* o = out + dst * NF + f4 * 4;
    atomicAdd(o + 0, w * s0.x);
    atomicAdd(o + 1, w * s0.y);
    atomicAdd(o + 2, w * s1.x);
    atomicAdd(o + 3, w * s1.y);
}

// ---------------------------------------------------------------------------
extern "C" void kernel_launch(void* const* d_in, const int* in_sizes, int n_in,
                              void* d_out, int out_size, void* d_ws, size_t ws_size,
                              hipStream_t stream) {
    const float* feat = (const float*)d_in[0];
    const void*  ei   = d_in[1];
    const float* ew   = (const float*)d_in[2];
    const float* W    = (const float*)d_in[3];
    const float* bias = (const float*)d_in[4];
    const int*   nm   = (const int*)d_in[5];

    int N = in_sizes[0] / NF;       // 100000
    int E = in_sizes[2];            // 1600000
    int NB = (N + SCHUNK - 1) / SCHUNK;   // scan blocks (196); must be <= 1024

    // workspace layout
    size_t off = 0;
    __half* support = (__half*)d_ws;                    off += (size_t)N * NF * sizeof(__half);
    float2* srcw    = (float2*)((char*)d_ws + off);     off += (size_t)E * sizeof(float2);
    int*    counts  = (int*)((char*)d_ws + off);        off += (size_t)N * sizeof(int);
    int*    offs    = (int*)((char*)d_ws + off);        off += (size_t)(N + 1) * sizeof(int);
    int*    cursor  = (int*)((char*)d_ws + off);        off += (size_t)N * sizeof(int);
    int*    bsum    = (int*)((char*)d_ws + off);        off += (size_t)NB * sizeof(int);
    int*    boff    = (int*)((char*)d_ws + off);        off += (size_t)NB * sizeof(int);
    int*    flag    = (int*)((char*)d_ws + off);        off += sizeof(int);
    bool use_csr = (ws_size >= off) && (NB <= 1024);

    detect_kernel<<<1, 64, 0, stream>>>((const int*)ei, flag);
    gemm_kernel<<<(N + GEMM_ROWS - 1) / GEMM_ROWS, 256, 0, stream>>>(feat, W, support, N);

    if (use_csr) {
        zero_kernel<<<(N + 255) / 256, 256, 0, stream>>>(counts, N);
        count_kernel<<<(E + 255) / 256, 256, 0, stream>>>(ei, counts, E, flag, nm);
        scanA_kernel<<<NB, 256, 0, stream>>>(counts, bsum, N);
        scanB_kernel<<<1, 1024, 0, stream>>>(bsum, boff, offs, NB, N);
        scanC_kernel<<<NB, 256, 0, stream>>>(counts, boff, offs, cursor, N);
        int nchunks = (E + FCHUNK - 1) / FCHUNK;
        fill_kernel<<<nchunks * NWIN, 256, 0, stream>>>(ei, ew, cursor, srcw, E, N,
                                                        flag, nm);
        long long gthreads = (long long)N * 64;
        gather_kernel<<<(int)((gthreads + 255) / 256), 256, 0, stream>>>(
            offs, srcw, support, bias, feat, (float*)d_out, N, nm);
    } else {
        int total4 = N * (NF / 4);
        init_kernel<<<(total4 + 255) / 256, 256, 0, stream>>>(bias, feat, (float*)d_out,
                                                              total4, nm);
        long long sthreads = (long long)E * 32;
        scatter_kernel<<<(int)((sthreads + 255) / 256), 256, 0, stream>>>(
            ei, ew, support, (float*)d_out, E, flag, nm);
    }
}